// Round 4
// baseline (82.159 us; speedup 1.0000x reference)
//
#include <hip/hip_runtime.h>

// Bilinear warp: out[n,y,x,c] = 4-corner bilinear sample of x at (x+dx, y+dy),
// zero padding outside. N=4, H=W=1024, C=8, fp32.
//
// R8: 4-lanes-per-pixel gather restructure (attacks TA request rate).
// Key fact: for one pixel, corner data (y, x0..x1, c0..7) is ONE contiguous
// 64-B span per corner row (x-stride = 32 B). The old 2-lane layout fetched it
// as 4 separate instructions x 32-B segments -> 4 TA segment-requests/px.
// New: lane role r = tid&3 (bit0 = channel half, bit1 = x corner); each lane
// loads 16 B per corner row, so ONE instruction covers the whole 64-B span
// (16 px x 64-B contiguous segments per instruction). Gather instrs/px: 4 -> 2.
// Cross-corner reduce: __shfl_xor(s, 2); store exec-masked to lanes r<2
// (float4 nt, coalesced, same store instruction count).
// Keeps R7's nt flow loads / nt out stores (84.5 -> 76.0 us win).

typedef float vf2 __attribute__((ext_vector_type(2)));
typedef float vf4 __attribute__((ext_vector_type(4)));

__global__ __launch_bounds__(256) void Warp_41446434406635_kernel(
    const float* __restrict__ img,   // [N, H, W, C]
    const float* __restrict__ flow,  // [N, H, W, 2]
    float* __restrict__ out)         // [N, H, W, C]
{
    const int W = 1024, H = 1024;

    int tid = blockIdx.x * 256 + threadIdx.x;
    int p = tid >> 2;          // pixel index (4 lanes cooperate per pixel)
    int r = tid & 3;           // bit0 = channel half, bit1 = x corner

    // all 4 lanes of a pixel read the same 8 B (TA broadcast); nt: zero reuse
    vf2 f = __builtin_nontemporal_load(reinterpret_cast<const vf2*>(flow) + p);

    int x = p & (W - 1), y = (p >> 10) & (H - 1), n = p >> 20;

    float gx = (float)x + f.x, gy = (float)y + f.y;
    float x0f = floorf(gx), y0f = floorf(gy);
    int ix0 = (int)x0f, iy0 = (int)y0f;
    int iy1 = iy0 + 1;
    float wx1 = gx - x0f, wy1 = gy - y0f;

    // this lane's x corner and x-weight (zero if out of bounds)
    int xr = ix0 + (r >> 1);
    float wxl = (r >> 1) ? wx1 : (1.0f - wx1);
    if ((xr < 0) | (xr >= W)) wxl = 0.0f;
    float wy0v = ((iy0 >= 0) & (iy0 < H)) ? (1.0f - wy1) : 0.0f;
    float wy1v = ((iy1 >= 0) & (iy1 < H)) ? wy1 : 0.0f;
    float w0 = wy0v * wxl;     // weight for corner row y0
    float w1 = wy1v * wxl;     // weight for corner row y1

    int cx  = min(max(xr, 0), W - 1);
    int cy0 = min(max(iy0, 0), H - 1);
    int cy1 = min(max(iy1, 0), H - 1);

    // n*H*W*C = n<<23 ; y*W*C = y<<13 ; x*C = x<<3 ; +4 floats if channel-hi
    // Lanes r=0..3 of a pixel hit byte offsets +0,+16,+32,+48 of the same
    // 64-B span -> one contiguous segment per pixel per instruction.
    const float* base = img + ((size_t)n << 23) + (cx << 3) + ((r & 1) << 2);
    vf4 v0 = *reinterpret_cast<const vf4*>(base + ((size_t)cy0 << 13));
    vf4 v1 = *reinterpret_cast<const vf4*>(base + ((size_t)cy1 << 13));

    // per-lane partial: this x-corner's contribution to its channel half
    vf4 s;
    s.x = fmaf(w0, v0.x, w1 * v1.x);
    s.y = fmaf(w0, v0.y, w1 * v1.y);
    s.z = fmaf(w0, v0.z, w1 * v1.z);
    s.w = fmaf(w0, v0.w, w1 * v1.w);

    // sum the two x-corners: partner lane is r^2 (same channel half)
    vf4 o;
    o.x = s.x + __shfl_xor(s.x, 2);
    o.y = s.y + __shfl_xor(s.y, 2);
    o.z = s.z + __shfl_xor(s.z, 2);
    o.w = s.w + __shfl_xor(s.w, 2);

    // lanes r=0,1 hold the full result for channel halves 0,1 -> masked store.
    // Active-lane addresses remain contiguous (512 B per wave store instr).
    if (r < 2) {
        vf4* o4 = reinterpret_cast<vf4*>(out);
        __builtin_nontemporal_store(o, o4 + ((size_t)p << 1) + (r & 1));
    }

    (void)H;
}

extern "C" void kernel_launch(void* const* d_in, const int* in_sizes, int n_in,
                              void* d_out, int out_size, void* d_ws, size_t ws_size,
                              hipStream_t stream) {
    const float* x = (const float*)d_in[0];
    const float* u = (const float*)d_in[1];
    float* out = (float*)d_out;

    // 4M px * 4 lanes/px / 256 = 65536 blocks (exact)
    Warp_41446434406635_kernel<<<65536, 256, 0, stream>>>(x, u, out);
}